// Round 6
// baseline (583.810 us; speedup 1.0000x reference)
//
#include <hip/hip_runtime.h>
#include <math.h>

#define N_NODES 100000
#define N_EDGES 1200000
#define HIDDEN  64
#define SCAN_BLOCKS ((N_NODES + 1023) / 1024)   // 98
#define GATHER_BLOCKS (N_NODES / 8)             // 12500: 8 waves x 1 node/wave
#define GEMM_BLOCKS ((N_NODES + 63) / 64)       // 1563: 4 waves x 16 nodes
#define HEAD_BLOCKS (N_NODES / 4)               // 25000

// ---------------------------------------------------------------- utilities

__device__ __forceinline__ float bcastf(float v, int l) {
    return __uint_as_float(__builtin_amdgcn_readlane(__float_as_uint(v), (unsigned)l));
}

__global__ __launch_bounds__(256) void zero_u32(unsigned* __restrict__ p, int n) {
    int i = blockIdx.x * 256 + threadIdx.x;
    if (i < n) p[i] = 0u;
}

// ---------------------------------------------------------------- CSR build

__global__ __launch_bounds__(256) void hist_kernel(const int* __restrict__ dst,
                                                   unsigned* __restrict__ cnt) {
    int e = blockIdx.x * 256 + threadIdx.x;
    if (e < N_EDGES) atomicAdd(&cnt[dst[e]], 1u);
}

__global__ __launch_bounds__(256) void scan_partial(const unsigned* __restrict__ cnt,
                                                    unsigned* __restrict__ pre,
                                                    unsigned* __restrict__ bsum) {
    __shared__ unsigned lds[256];
    const int t = threadIdx.x;
    const int base = blockIdx.x * 1024 + t * 4;
    unsigned v0 = 0, v1 = 0, v2 = 0, v3 = 0;
    if (base < N_NODES) {
        const uint4 q = *(const uint4*)(cnt + base);
        v0 = q.x; v1 = q.y; v2 = q.z; v3 = q.w;
    }
    const unsigned s = v0 + v1 + v2 + v3;
    lds[t] = s;
    __syncthreads();
    for (int off = 1; off < 256; off <<= 1) {
        unsigned u = (t >= off) ? lds[t - off] : 0u;
        __syncthreads();
        lds[t] += u;
        __syncthreads();
    }
    const unsigned excl = lds[t] - s;
    if (base < N_NODES) {
        uint4 o;
        o.x = excl;
        o.y = excl + v0;
        o.z = excl + v0 + v1;
        o.w = excl + v0 + v1 + v2;
        *(uint4*)(pre + base) = o;
    }
    if (t == 255) bsum[blockIdx.x] = lds[255];
}

__global__ __launch_bounds__(128) void scan_bsum(unsigned* __restrict__ bsum) {
    __shared__ unsigned lds[128];
    const int t = threadIdx.x;
    unsigned s = (t < SCAN_BLOCKS) ? bsum[t] : 0u;
    lds[t] = s;
    __syncthreads();
    for (int off = 1; off < 128; off <<= 1) {
        unsigned u = (t >= off) ? lds[t - off] : 0u;
        __syncthreads();
        lds[t] += u;
        __syncthreads();
    }
    if (t < SCAN_BLOCKS) bsum[t] = lds[t] - s;
}

__global__ __launch_bounds__(256) void scan_final(const unsigned* __restrict__ cnt,
                                                  const unsigned* __restrict__ pre,
                                                  const unsigned* __restrict__ bsum,
                                                  unsigned* __restrict__ rowptr,
                                                  float* __restrict__ invcnt) {
    const int t = threadIdx.x;
    const int base = blockIdx.x * 1024 + t * 4;
    if (base < N_NODES) {
        const unsigned off = bsum[blockIdx.x];
        uint4 p = *(const uint4*)(pre + base);
        const uint4 cq = *(const uint4*)(cnt + base);
        p.x += off; p.y += off; p.z += off; p.w += off;
        *(uint4*)(rowptr + base) = p;
        float4 ic;
        ic.x = 1.0f / (float)(cq.x + 1u);
        ic.y = 1.0f / (float)(cq.y + 1u);
        ic.z = 1.0f / (float)(cq.z + 1u);
        ic.w = 1.0f / (float)(cq.w + 1u);
        *(float4*)(invcnt + base) = ic;
    }
    if (blockIdx.x == 0 && t == 0) rowptr[N_NODES] = N_EDGES;
}

__global__ __launch_bounds__(256) void fill_csr(const int* __restrict__ src,
                                                const int* __restrict__ dst,
                                                const unsigned* __restrict__ rowptr,
                                                unsigned* __restrict__ fillc,
                                                unsigned* __restrict__ csr) {
    int e = blockIdx.x * 256 + threadIdx.x;
    if (e < N_EDGES) {
        int d = dst[e];
        unsigned pos = rowptr[d] + atomicAdd(&fillc[d], 1u);
        csr[pos] = (unsigned)src[e];
    }
}

// ---------------------------------------------------------------- weight folding
// V2 = W @ U_bot [IN,64];  cp = c + b @ U_bot [64]
template <int IN>
__global__ __launch_bounds__(256) void precompute_v(const float* __restrict__ W,
                                                    const float* __restrict__ b,
                                                    const float* __restrict__ U,
                                                    const float* __restrict__ c,
                                                    float* __restrict__ V2,
                                                    float* __restrict__ cp) {
    __shared__ float Ub[64 * 64];
    const int tid = threadIdx.x;
    for (int j = tid; j < 64 * 64; j += 256) Ub[j] = U[IN * 64 + j];
    __syncthreads();
    const int w = tid >> 6, lane = tid & 63;
    const int r = blockIdx.x * 4 + w;
    if (r > IN) return;
    const float wv = (r < IN) ? W[r * 64 + lane] : b[lane];
    float o = (r < IN) ? 0.f : c[lane];
#pragma unroll 8
    for (int k = 0; k < 64; ++k) o += bcastf(wv, k) * Ub[k * 64 + lane];
    if (r < IN) V2[r * 64 + lane] = o;
    else        cp[lane] = o;
}

// ---------------------------------------------------------------- gather-mean
// One node per wave. m[n,:] = (hprev[n,:] + sum_in-edges hprev[src,:]) * invcnt[n].
// All control values (n, rowptr, csr words) forced wave-uniform -> scalar pipe;
// the only VALU work is the adds. 8 row-loads in flight per wave.
template <int IN>
__global__ __launch_bounds__(512) void gather_mean(const float* __restrict__ hprev,
                                                   const unsigned* __restrict__ csr,
                                                   const unsigned* __restrict__ rowptr,
                                                   const float* __restrict__ invcnt,
                                                   float* __restrict__ m_out) {
    const int tid = threadIdx.x;
    const int wv = __builtin_amdgcn_readfirstlane(tid >> 6);   // uniform wave id
    const int lane = tid & 63;
    const int n = blockIdx.x * 8 + wv;                         // uniform
    const unsigned e0 = rowptr[n], e1 = rowptr[n + 1];         // s_load

    float m = (lane < IN) ? hprev[(size_t)n * IN + lane] : 0.f;   // self loop
    unsigned e = e0;
    for (; e + 8 <= e1; e += 8) {
        const unsigned i0 = csr[e + 0], i1 = csr[e + 1], i2 = csr[e + 2], i3 = csr[e + 3];
        const unsigned i4 = csr[e + 4], i5 = csr[e + 5], i6 = csr[e + 6], i7 = csr[e + 7];
        const float a0 = (lane < IN) ? hprev[(size_t)i0 * IN + lane] : 0.f;
        const float a1 = (lane < IN) ? hprev[(size_t)i1 * IN + lane] : 0.f;
        const float a2 = (lane < IN) ? hprev[(size_t)i2 * IN + lane] : 0.f;
        const float a3 = (lane < IN) ? hprev[(size_t)i3 * IN + lane] : 0.f;
        const float a4 = (lane < IN) ? hprev[(size_t)i4 * IN + lane] : 0.f;
        const float a5 = (lane < IN) ? hprev[(size_t)i5 * IN + lane] : 0.f;
        const float a6 = (lane < IN) ? hprev[(size_t)i6 * IN + lane] : 0.f;
        const float a7 = (lane < IN) ? hprev[(size_t)i7 * IN + lane] : 0.f;
        m += ((a0 + a1) + (a2 + a3)) + ((a4 + a5) + (a6 + a7));
    }
    for (; e + 4 <= e1; e += 4) {
        const unsigned i0 = csr[e + 0], i1 = csr[e + 1], i2 = csr[e + 2], i3 = csr[e + 3];
        const float a0 = (lane < IN) ? hprev[(size_t)i0 * IN + lane] : 0.f;
        const float a1 = (lane < IN) ? hprev[(size_t)i1 * IN + lane] : 0.f;
        const float a2 = (lane < IN) ? hprev[(size_t)i2 * IN + lane] : 0.f;
        const float a3 = (lane < IN) ? hprev[(size_t)i3 * IN + lane] : 0.f;
        m += (a0 + a1) + (a2 + a3);
    }
    for (; e < e1; ++e)
        m += (lane < IN) ? hprev[(size_t)csr[e] * IN + lane] : 0.f;

    if (lane < IN) m_out[(size_t)n * IN + lane] = m * invcnt[n];
}

// ---------------------------------------------------------------- update GEMM
// h[n,:] = relu( hprev[n,:]@Utop + m[n,:]@V2 + cp )
// Wave = 16-node tile; weights staged once per block in LDS; A-operands are
// wave-uniform scalar loads (s_load) -> v_fmac with 1 SGPR operand.
// FMA/node = 2*IN (the floor); LDS reads/node ~ 2*IN/16.
template <int IN>
__global__ __launch_bounds__(256) void update_gemm(const float* __restrict__ hprev,
                                                   const float* __restrict__ m_in,
                                                   const float* __restrict__ Utop,
                                                   const float* __restrict__ V2,
                                                   const float* __restrict__ cp,
                                                   float* __restrict__ hnext) {
    __shared__ float B[2 * IN * 64];           // rows 0..IN-1: Utop, IN..2IN-1: V2
    const int tid = threadIdx.x;
    for (int j = tid; j < IN * 64; j += 256) {
        B[j] = Utop[j];
        B[IN * 64 + j] = V2[j];
    }
    __syncthreads();
    const int wv = __builtin_amdgcn_readfirstlane(tid >> 6);   // uniform
    const int lane = tid & 63;
    const int base = blockIdx.x * 64 + wv * 16;                // uniform; N%16==0
    if (base >= N_NODES) return;

    float acc[16];
    const float cpl = cp[lane];
#pragma unroll
    for (int i = 0; i < 16; ++i) acc[i] = cpl;

    if constexpr (IN == 64) {
        // hp part
        for (int k = 0; k < 64; k += 4) {
            const float u0 = B[(k + 0) * 64 + lane];
            const float u1 = B[(k + 1) * 64 + lane];
            const float u2 = B[(k + 2) * 64 + lane];
            const float u3 = B[(k + 3) * 64 + lane];
#pragma unroll
            for (int i = 0; i < 16; ++i) {
                const float4 a = *(const float4*)(hprev + (size_t)(base + i) * 64 + k);
                acc[i] += (a.x * u0 + a.y * u1) + (a.z * u2 + a.w * u3);
            }
        }
        // m part
        for (int k = 0; k < 64; k += 4) {
            const float u0 = B[(64 + k + 0) * 64 + lane];
            const float u1 = B[(64 + k + 1) * 64 + lane];
            const float u2 = B[(64 + k + 2) * 64 + lane];
            const float u3 = B[(64 + k + 3) * 64 + lane];
#pragma unroll
            for (int i = 0; i < 16; ++i) {
                const float4 a = *(const float4*)(m_in + (size_t)(base + i) * 64 + k);
                acc[i] += (a.x * u0 + a.y * u1) + (a.z * u2 + a.w * u3);
            }
        }
    } else {
#pragma unroll
        for (int k = 0; k < IN; ++k) {
            const float u0 = B[k * 64 + lane];
            const float u1 = B[(IN + k) * 64 + lane];
#pragma unroll
            for (int i = 0; i < 16; ++i) {
                acc[i] += hprev[(size_t)(base + i) * IN + k] * u0
                        + m_in [(size_t)(base + i) * IN + k] * u1;
            }
        }
    }

#pragma unroll
    for (int i = 0; i < 16; ++i)
        hnext[(size_t)(base + i) * 64 + lane] = fmaxf(acc[i], 0.f);
}

// ---------------------------------------------------------------- heads

__global__ __launch_bounds__(256) void heads_kernel(const float* __restrict__ h,
                                                    const float* __restrict__ Ws,
                                                    const float* __restrict__ bs,
                                                    const float* __restrict__ Wst,
                                                    const float* __restrict__ bst,
                                                    const float* __restrict__ Wo,
                                                    const float* __restrict__ bo,
                                                    float* __restrict__ state,
                                                    float* __restrict__ part) {
    const int tid = threadIdx.x, w = tid >> 6, lane = tid & 63;
    const int n = blockIdx.x * 4 + w;
    float hv = h[n * 64 + lane];
    float s0 = hv * Ws[lane * 2 + 0];
    float s1 = hv * Ws[lane * 2 + 1];
    float st = hv * Wst[lane];
    float oc = hv * Wo[lane];
#pragma unroll
    for (int off = 32; off; off >>= 1) {
        s0 += __shfl_down(s0, off);
        s1 += __shfl_down(s1, off);
        st += __shfl_down(st, off);
        oc += __shfl_down(oc, off);
    }
    __shared__ float red[4][2];
    if (lane == 0) {
        state[n * 2 + 0] = s0 + bs[0];
        state[n * 2 + 1] = s1 + bs[1];
        red[w][0] = 1.0f / (1.0f + __expf(-(st + bst[0])));
        red[w][1] = oc + bo[0];
    }
    __syncthreads();
    if (tid == 0) {
        part[blockIdx.x * 2 + 0] = red[0][0] + red[1][0] + red[2][0] + red[3][0];
        part[blockIdx.x * 2 + 1] = red[0][1] + red[1][1] + red[2][1] + red[3][1];
    }
}

__global__ __launch_bounds__(1024) void final_reduce(const float* __restrict__ part,
                                                     float* __restrict__ scal) {
    __shared__ float l0[1024], l1[1024];
    const int t = threadIdx.x;
    float a = 0.f, b = 0.f;
    for (int i = t; i < HEAD_BLOCKS; i += 1024) { a += part[2 * i]; b += part[2 * i + 1]; }
    l0[t] = a; l1[t] = b;
    __syncthreads();
    for (int off = 512; off; off >>= 1) {
        if (t < off) { l0[t] += l0[t + off]; l1[t] += l1[t + off]; }
        __syncthreads();
    }
    if (t == 0) {
        scal[0] = l0[0] / (float)N_NODES;   // stability
        scal[1] = l1[0] / (float)N_NODES;   // opf_cost
    }
}

// ---------------------------------------------------------------- launch

extern "C" void kernel_launch(void* const* d_in, const int* in_sizes, int n_in,
                              void* d_out, int out_size, void* d_ws, size_t ws_size,
                              hipStream_t stream) {
    const float* x   = (const float*)d_in[0];
    const int*   ei  = (const int*)d_in[1];
    const float* W1  = (const float*)d_in[2];
    const float* b1  = (const float*)d_in[3];
    const float* U1  = (const float*)d_in[4];
    const float* c1  = (const float*)d_in[5];
    const float* W2  = (const float*)d_in[6];
    const float* b2  = (const float*)d_in[7];
    const float* U2  = (const float*)d_in[8];
    const float* c2  = (const float*)d_in[9];
    const float* W3  = (const float*)d_in[10];
    const float* b3  = (const float*)d_in[11];
    const float* U3  = (const float*)d_in[12];
    const float* c3  = (const float*)d_in[13];
    const float* Ws  = (const float*)d_in[14];
    const float* bs  = (const float*)d_in[15];
    const float* Wst = (const float*)d_in[16];
    const float* bst = (const float*)d_in[17];
    const float* Wo  = (const float*)d_in[18];
    const float* bo  = (const float*)d_in[19];

    const int* src = ei;              // edge_index[0]
    const int* dst = ei + N_EDGES;    // edge_index[1]

    char* wsp = (char*)d_ws;
    size_t off = 0;
    auto alloc = [&](size_t bytes) -> char* {
        char* p = wsp + off;
        off = (off + bytes + 255) & ~(size_t)255;
        return p;
    };
    unsigned* cnt    = (unsigned*)alloc((size_t)N_NODES * 4);
    unsigned* fillc  = (unsigned*)alloc((size_t)N_NODES * 4);
    unsigned* rowptr = (unsigned*)alloc((size_t)(N_NODES + 1) * 4);
    float*    invcnt = (float*)   alloc((size_t)N_NODES * 4);
    unsigned* pre    = (unsigned*)alloc((size_t)N_NODES * 4);
    unsigned* bsum   = (unsigned*)alloc((size_t)SCAN_BLOCKS * 4);
    unsigned* csr    = (unsigned*)alloc((size_t)N_EDGES * 4);
    float*    part   = (float*)   alloc((size_t)HEAD_BLOCKS * 2 * 4);
    float*    V2a    = (float*)   alloc((size_t)5 * 64 * 4);
    float*    V2b    = (float*)   alloc((size_t)64 * 64 * 4);
    float*    V2c    = (float*)   alloc((size_t)64 * 64 * 4);
    float*    cpa    = (float*)   alloc((size_t)64 * 4);
    float*    cpb    = (float*)   alloc((size_t)64 * 4);
    float*    cpc    = (float*)   alloc((size_t)64 * 4);
    float*    hA     = (float*)   alloc((size_t)N_NODES * HIDDEN * 4);
    float*    hB     = (float*)   alloc((size_t)N_NODES * HIDDEN * 4);
    float*    mbuf   = (float*)   alloc((size_t)N_NODES * HIDDEN * 4);

    float* out   = (float*)d_out;
    float* state = out;                 // [N, 2]
    float* scal  = out + 200000;        // stability, opf_cost
    float* hout  = out + 200002;        // [N, 64]

    const int EB = (N_EDGES + 255) / 256;   // 4688
    const int NB = (N_NODES + 255) / 256;   // 391

    // weight folding (graph-independent)
    precompute_v<5> <<<2, 256, 0, stream>>>(W1, b1, U1, c1, V2a, cpa);
    precompute_v<64><<<17, 256, 0, stream>>>(W2, b2, U2, c2, V2b, cpb);
    precompute_v<64><<<17, 256, 0, stream>>>(W3, b3, U3, c3, V2c, cpc);

    // CSR build (exact-extent zeroing — see R1 poison bug)
    zero_u32<<<NB, 256, 0, stream>>>(cnt,   N_NODES);
    zero_u32<<<NB, 256, 0, stream>>>(fillc, N_NODES);
    hist_kernel<<<EB, 256, 0, stream>>>(dst, cnt);
    scan_partial<<<SCAN_BLOCKS, 256, 0, stream>>>(cnt, pre, bsum);
    scan_bsum<<<1, 128, 0, stream>>>(bsum);
    scan_final<<<SCAN_BLOCKS, 256, 0, stream>>>(cnt, pre, bsum, rowptr, invcnt);
    fill_csr<<<EB, 256, 0, stream>>>(src, dst, rowptr, fillc, csr);

    // layer 1 (IN=5): mbuf holds m5 [N,5]
    gather_mean<5> <<<GATHER_BLOCKS, 512, 0, stream>>>(x, csr, rowptr, invcnt, mbuf);
    update_gemm<5> <<<GEMM_BLOCKS, 256, 0, stream>>>(x, mbuf, U1, V2a, cpa, hA);
    // layer 2 (IN=64)
    gather_mean<64><<<GATHER_BLOCKS, 512, 0, stream>>>(hA, csr, rowptr, invcnt, mbuf);
    update_gemm<64><<<GEMM_BLOCKS, 256, 0, stream>>>(hA, mbuf, U2, V2b, cpb, hB);
    // layer 3 (IN=64): hA is dead — reuse as m buffer; output straight to d_out
    gather_mean<64><<<GATHER_BLOCKS, 512, 0, stream>>>(hB, csr, rowptr, invcnt, hA);
    update_gemm<64><<<GEMM_BLOCKS, 256, 0, stream>>>(hB, hA, U3, V2c, cpc, hout);

    // heads
    heads_kernel<<<HEAD_BLOCKS, 256, 0, stream>>>(hout, Ws, bs, Wst, bst, Wo, bo, state, part);
    final_reduce<<<1, 1024, 0, stream>>>(part, scal);
}

// Round 7
// 413.347 us; speedup vs baseline: 1.4124x; 1.4124x over previous
//
#include <hip/hip_runtime.h>
#include <math.h>

#define N_NODES 100000
#define N_EDGES 1200000
#define HIDDEN  64
#define SCAN_BLOCKS ((N_NODES + 1023) / 1024)   // 98
#define LAYER_BLOCKS (N_NODES / 32)             // 3125: 8 waves, 4 nodes/wave
#define HEAD_BLOCKS (N_NODES / 4)               // 25000

// ---------------------------------------------------------------- utilities

__device__ __forceinline__ float bcastf(float v, int l) {
    return __uint_as_float(__builtin_amdgcn_readlane(__float_as_uint(v), (unsigned)l));
}

__global__ __launch_bounds__(256) void zero_u32(unsigned* __restrict__ p, int n) {
    int i = blockIdx.x * 256 + threadIdx.x;
    if (i < n) p[i] = 0u;
}

// ---------------------------------------------------------------- CSR build

// hist + rank capture: rank[e] = this edge's slot within its dst bucket.
// The atomic return value is free — this is what makes fill_csr atomic-free.
__global__ __launch_bounds__(256) void hist_kernel(const int* __restrict__ dst,
                                                   unsigned* __restrict__ cnt,
                                                   unsigned* __restrict__ rank) {
    int e = blockIdx.x * 256 + threadIdx.x;
    if (e < N_EDGES) rank[e] = atomicAdd(&cnt[dst[e]], 1u);
}

__global__ __launch_bounds__(256) void scan_partial(const unsigned* __restrict__ cnt,
                                                    unsigned* __restrict__ pre,
                                                    unsigned* __restrict__ bsum) {
    __shared__ unsigned lds[256];
    const int t = threadIdx.x;
    const int base = blockIdx.x * 1024 + t * 4;
    unsigned v0 = 0, v1 = 0, v2 = 0, v3 = 0;
    if (base < N_NODES) {
        const uint4 q = *(const uint4*)(cnt + base);
        v0 = q.x; v1 = q.y; v2 = q.z; v3 = q.w;
    }
    const unsigned s = v0 + v1 + v2 + v3;
    lds[t] = s;
    __syncthreads();
    for (int off = 1; off < 256; off <<= 1) {
        unsigned u = (t >= off) ? lds[t - off] : 0u;
        __syncthreads();
        lds[t] += u;
        __syncthreads();
    }
    const unsigned excl = lds[t] - s;
    if (base < N_NODES) {
        uint4 o;
        o.x = excl;
        o.y = excl + v0;
        o.z = excl + v0 + v1;
        o.w = excl + v0 + v1 + v2;
        *(uint4*)(pre + base) = o;
    }
    if (t == 255) bsum[blockIdx.x] = lds[255];
}

__global__ __launch_bounds__(128) void scan_bsum(unsigned* __restrict__ bsum) {
    __shared__ unsigned lds[128];
    const int t = threadIdx.x;
    unsigned s = (t < SCAN_BLOCKS) ? bsum[t] : 0u;
    lds[t] = s;
    __syncthreads();
    for (int off = 1; off < 128; off <<= 1) {
        unsigned u = (t >= off) ? lds[t - off] : 0u;
        __syncthreads();
        lds[t] += u;
        __syncthreads();
    }
    if (t < SCAN_BLOCKS) bsum[t] = lds[t] - s;
}

__global__ __launch_bounds__(256) void scan_final(const unsigned* __restrict__ cnt,
                                                  const unsigned* __restrict__ pre,
                                                  const unsigned* __restrict__ bsum,
                                                  unsigned* __restrict__ rowptr,
                                                  float* __restrict__ invcnt) {
    const int t = threadIdx.x;
    const int base = blockIdx.x * 1024 + t * 4;
    if (base < N_NODES) {
        const unsigned off = bsum[blockIdx.x];
        uint4 p = *(const uint4*)(pre + base);
        const uint4 cq = *(const uint4*)(cnt + base);
        p.x += off; p.y += off; p.z += off; p.w += off;
        *(uint4*)(rowptr + base) = p;
        float4 ic;
        ic.x = 1.0f / (float)(cq.x + 1u);
        ic.y = 1.0f / (float)(cq.y + 1u);
        ic.z = 1.0f / (float)(cq.z + 1u);
        ic.w = 1.0f / (float)(cq.w + 1u);
        *(float4*)(invcnt + base) = ic;
    }
    if (blockIdx.x == 0 && t == 0) rowptr[N_NODES] = N_EDGES;
}

// atomic-free: pos = rowptr[dst] + rank (rank captured in hist)
__global__ __launch_bounds__(256) void fill_csr(const int* __restrict__ src,
                                                const int* __restrict__ dst,
                                                const unsigned* __restrict__ rowptr,
                                                const unsigned* __restrict__ rank,
                                                unsigned* __restrict__ csr) {
    int e = blockIdx.x * 256 + threadIdx.x;
    if (e < N_EDGES) {
        const int d = dst[e];
        csr[rowptr[d] + rank[e]] = (unsigned)src[e];
    }
}

// ---------------------------------------------------------------- weight folding
// V2 = W @ U_bot [IN,64];  cp = c + b @ U_bot [64]
template <int IN>
__global__ __launch_bounds__(256) void precompute_v(const float* __restrict__ W,
                                                    const float* __restrict__ b,
                                                    const float* __restrict__ U,
                                                    const float* __restrict__ c,
                                                    float* __restrict__ V2,
                                                    float* __restrict__ cp) {
    __shared__ float Ub[64 * 64];
    const int tid = threadIdx.x;
    for (int j = tid; j < 64 * 64; j += 256) Ub[j] = U[IN * 64 + j];
    __syncthreads();
    const int w = tid >> 6, lane = tid & 63;
    const int r = blockIdx.x * 4 + w;
    if (r > IN) return;
    const float wv = (r < IN) ? W[r * 64 + lane] : b[lane];
    float o = (r < IN) ? 0.f : c[lane];
#pragma unroll 8
    for (int k = 0; k < 64; ++k) o += bcastf(wv, k) * Ub[k * 64 + lane];
    if (r < IN) V2[r * 64 + lane] = o;
    else        cp[lane] = o;
}

// ---------------------------------------------------------------- fused layer
// h[n,:] = relu( hprev[n,:]@Utop + m[n,:]@V2 + cp ),
// m = mean over in-edges+self of hprev rows.
// Block = 512 thr / 8 waves / 32 nodes. Phase 1: each wave gathers 4 nodes
// (R5-style, loads in flight, no cross-wave coupling) and deposits (hp_k, m_k)
// float2 pairs in LDS. Phase 2: each wave GEMMs its 4-node register tile:
// per k: 1 ds_read_b64 weights + 4 uniform-addr broadcast reads + 8 FMA.
// Weight-LDS traffic/node = 8 KB (was 32 KB in R5); zero readlanes.
template <int IN>
__global__ __launch_bounds__(512) void fused_layer(const float* __restrict__ hprev,
                                                   const unsigned* __restrict__ csr,
                                                   const unsigned* __restrict__ rowptr,
                                                   const float* __restrict__ invcnt,
                                                   const float* __restrict__ Utop,
                                                   const float* __restrict__ V2,
                                                   const float* __restrict__ cp,
                                                   float* __restrict__ hnext) {
    __shared__ float2 T[IN * 64];     // (Utop[k][lane], V2[k][lane])   32 KiB @ IN=64
    __shared__ float2 A[32 * IN];     // (hp[k], m[k]) per local node   16 KiB @ IN=64
    const int tid = threadIdx.x;
    for (int j = tid; j < IN * 64; j += 512) T[j] = make_float2(Utop[j], V2[j]);
    const int wv = __builtin_amdgcn_readfirstlane(tid >> 6);   // uniform wave id
    const int lane = tid & 63;
    const int nb = blockIdx.x * 32;

    // ---- phase 1: gather-mean, 4 nodes per wave
    for (int i = 0; i < 4; ++i) {
        const int loc = wv * 4 + i;
        const int n = nb + loc;
        const unsigned e0 = rowptr[n], e1 = rowptr[n + 1];
        const float hp = (lane < IN) ? hprev[(size_t)n * IN + lane] : 0.f;
        float m = hp;                                          // self loop
        unsigned e = e0;
        for (; e + 8 <= e1; e += 8) {                          // 8 rows in flight
            const unsigned i0 = csr[e + 0], i1 = csr[e + 1], i2 = csr[e + 2], i3 = csr[e + 3];
            const unsigned i4 = csr[e + 4], i5 = csr[e + 5], i6 = csr[e + 6], i7 = csr[e + 7];
            const float a0 = (lane < IN) ? hprev[(size_t)i0 * IN + lane] : 0.f;
            const float a1 = (lane < IN) ? hprev[(size_t)i1 * IN + lane] : 0.f;
            const float a2 = (lane < IN) ? hprev[(size_t)i2 * IN + lane] : 0.f;
            const float a3 = (lane < IN) ? hprev[(size_t)i3 * IN + lane] : 0.f;
            const float a4 = (lane < IN) ? hprev[(size_t)i4 * IN + lane] : 0.f;
            const float a5 = (lane < IN) ? hprev[(size_t)i5 * IN + lane] : 0.f;
            const float a6 = (lane < IN) ? hprev[(size_t)i6 * IN + lane] : 0.f;
            const float a7 = (lane < IN) ? hprev[(size_t)i7 * IN + lane] : 0.f;
            m += ((a0 + a1) + (a2 + a3)) + ((a4 + a5) + (a6 + a7));
        }
        for (; e + 4 <= e1; e += 4) {
            const unsigned i0 = csr[e + 0], i1 = csr[e + 1], i2 = csr[e + 2], i3 = csr[e + 3];
            const float a0 = (lane < IN) ? hprev[(size_t)i0 * IN + lane] : 0.f;
            const float a1 = (lane < IN) ? hprev[(size_t)i1 * IN + lane] : 0.f;
            const float a2 = (lane < IN) ? hprev[(size_t)i2 * IN + lane] : 0.f;
            const float a3 = (lane < IN) ? hprev[(size_t)i3 * IN + lane] : 0.f;
            m += (a0 + a1) + (a2 + a3);
        }
        for (; e < e1; ++e)
            m += (lane < IN) ? hprev[(size_t)csr[e] * IN + lane] : 0.f;
        if (lane < IN) A[loc * IN + lane] = make_float2(hp, m * invcnt[n]);
    }
    __syncthreads();

    // ---- phase 2: 4-node register-tile GEMM
    const float cpl = cp[lane];
    float acc0 = cpl, acc1 = cpl, acc2 = cpl, acc3 = cpl;
    const int ab = wv * 4 * IN;
#pragma unroll 8
    for (int k = 0; k < IN; ++k) {
        const float2 t = T[k * 64 + lane];
        const float2 a0 = A[ab + k];               // uniform addr -> LDS broadcast
        const float2 a1 = A[ab + IN + k];
        const float2 a2 = A[ab + 2 * IN + k];
        const float2 a3 = A[ab + 3 * IN + k];
        acc0 += a0.x * t.x + a0.y * t.y;
        acc1 += a1.x * t.x + a1.y * t.y;
        acc2 += a2.x * t.x + a2.y * t.y;
        acc3 += a3.x * t.x + a3.y * t.y;
    }
    const size_t n0 = (size_t)(nb + wv * 4) * 64 + lane;
    hnext[n0]       = fmaxf(acc0, 0.f);
    hnext[n0 + 64]  = fmaxf(acc1, 0.f);
    hnext[n0 + 128] = fmaxf(acc2, 0.f);
    hnext[n0 + 192] = fmaxf(acc3, 0.f);
}

// ---------------------------------------------------------------- heads

__global__ __launch_bounds__(256) void heads_kernel(const float* __restrict__ h,
                                                    const float* __restrict__ Ws,
                                                    const float* __restrict__ bs,
                                                    const float* __restrict__ Wst,
                                                    const float* __restrict__ bst,
                                                    const float* __restrict__ Wo,
                                                    const float* __restrict__ bo,
                                                    float* __restrict__ state,
                                                    float* __restrict__ part) {
    const int tid = threadIdx.x, w = tid >> 6, lane = tid & 63;
    const int n = blockIdx.x * 4 + w;
    float hv = h[n * 64 + lane];
    float s0 = hv * Ws[lane * 2 + 0];
    float s1 = hv * Ws[lane * 2 + 1];
    float st = hv * Wst[lane];
    float oc = hv * Wo[lane];
#pragma unroll
    for (int off = 32; off; off >>= 1) {
        s0 += __shfl_down(s0, off);
        s1 += __shfl_down(s1, off);
        st += __shfl_down(st, off);
        oc += __shfl_down(oc, off);
    }
    __shared__ float red[4][2];
    if (lane == 0) {
        state[n * 2 + 0] = s0 + bs[0];
        state[n * 2 + 1] = s1 + bs[1];
        red[w][0] = 1.0f / (1.0f + __expf(-(st + bst[0])));
        red[w][1] = oc + bo[0];
    }
    __syncthreads();
    if (tid == 0) {
        part[blockIdx.x * 2 + 0] = red[0][0] + red[1][0] + red[2][0] + red[3][0];
        part[blockIdx.x * 2 + 1] = red[0][1] + red[1][1] + red[2][1] + red[3][1];
    }
}

__global__ __launch_bounds__(1024) void final_reduce(const float* __restrict__ part,
                                                     float* __restrict__ scal) {
    __shared__ float l0[1024], l1[1024];
    const int t = threadIdx.x;
    float a = 0.f, b = 0.f;
    for (int i = t; i < HEAD_BLOCKS; i += 1024) { a += part[2 * i]; b += part[2 * i + 1]; }
    l0[t] = a; l1[t] = b;
    __syncthreads();
    for (int off = 512; off; off >>= 1) {
        if (t < off) { l0[t] += l0[t + off]; l1[t] += l1[t + off]; }
        __syncthreads();
    }
    if (t == 0) {
        scal[0] = l0[0] / (float)N_NODES;   // stability
        scal[1] = l1[0] / (float)N_NODES;   // opf_cost
    }
}

// ---------------------------------------------------------------- launch

extern "C" void kernel_launch(void* const* d_in, const int* in_sizes, int n_in,
                              void* d_out, int out_size, void* d_ws, size_t ws_size,
                              hipStream_t stream) {
    const float* x   = (const float*)d_in[0];
    const int*   ei  = (const int*)d_in[1];
    const float* W1  = (const float*)d_in[2];
    const float* b1  = (const float*)d_in[3];
    const float* U1  = (const float*)d_in[4];
    const float* c1  = (const float*)d_in[5];
    const float* W2  = (const float*)d_in[6];
    const float* b2  = (const float*)d_in[7];
    const float* U2  = (const float*)d_in[8];
    const float* c2  = (const float*)d_in[9];
    const float* W3  = (const float*)d_in[10];
    const float* b3  = (const float*)d_in[11];
    const float* U3  = (const float*)d_in[12];
    const float* c3  = (const float*)d_in[13];
    const float* Ws  = (const float*)d_in[14];
    const float* bs  = (const float*)d_in[15];
    const float* Wst = (const float*)d_in[16];
    const float* bst = (const float*)d_in[17];
    const float* Wo  = (const float*)d_in[18];
    const float* bo  = (const float*)d_in[19];

    const int* src = ei;              // edge_index[0]
    const int* dst = ei + N_EDGES;    // edge_index[1]

    char* wsp = (char*)d_ws;
    size_t off = 0;
    auto alloc = [&](size_t bytes) -> char* {
        char* p = wsp + off;
        off = (off + bytes + 255) & ~(size_t)255;
        return p;
    };
    unsigned* cnt    = (unsigned*)alloc((size_t)N_NODES * 4);
    unsigned* rowptr = (unsigned*)alloc((size_t)(N_NODES + 1) * 4);
    float*    invcnt = (float*)   alloc((size_t)N_NODES * 4);
    unsigned* pre    = (unsigned*)alloc((size_t)N_NODES * 4);
    unsigned* bsum   = (unsigned*)alloc((size_t)SCAN_BLOCKS * 4);
    unsigned* rank   = (unsigned*)alloc((size_t)N_EDGES * 4);
    unsigned* csr    = (unsigned*)alloc((size_t)N_EDGES * 4);
    float*    part   = (float*)   alloc((size_t)HEAD_BLOCKS * 2 * 4);
    float*    V2a    = (float*)   alloc((size_t)5 * 64 * 4);
    float*    V2b    = (float*)   alloc((size_t)64 * 64 * 4);
    float*    V2c    = (float*)   alloc((size_t)64 * 64 * 4);
    float*    cpa    = (float*)   alloc((size_t)64 * 4);
    float*    cpb    = (float*)   alloc((size_t)64 * 4);
    float*    cpc    = (float*)   alloc((size_t)64 * 4);
    float*    hA     = (float*)   alloc((size_t)N_NODES * HIDDEN * 4);
    float*    hB     = (float*)   alloc((size_t)N_NODES * HIDDEN * 4);

    float* out   = (float*)d_out;
    float* state = out;                 // [N, 2]
    float* scal  = out + 200000;        // stability, opf_cost
    float* hout  = out + 200002;        // [N, 64]

    const int EB = (N_EDGES + 255) / 256;   // 4688
    const int NB = (N_NODES + 255) / 256;   // 391

    // weight folding (graph-independent)
    precompute_v<5> <<<2, 256, 0, stream>>>(W1, b1, U1, c1, V2a, cpa);
    precompute_v<64><<<17, 256, 0, stream>>>(W2, b2, U2, c2, V2b, cpb);
    precompute_v<64><<<17, 256, 0, stream>>>(W3, b3, U3, c3, V2c, cpc);

    // CSR build (exact-extent zeroing — see R1 poison bug)
    zero_u32<<<NB, 256, 0, stream>>>(cnt, N_NODES);
    hist_kernel<<<EB, 256, 0, stream>>>(dst, cnt, rank);
    scan_partial<<<SCAN_BLOCKS, 256, 0, stream>>>(cnt, pre, bsum);
    scan_bsum<<<1, 128, 0, stream>>>(bsum);
    scan_final<<<SCAN_BLOCKS, 256, 0, stream>>>(cnt, pre, bsum, rowptr, invcnt);
    fill_csr<<<EB, 256, 0, stream>>>(src, dst, rowptr, rank, csr);

    // layers: h = relu(hprev@U_top + mean@V2 + cp)
    fused_layer<5> <<<LAYER_BLOCKS, 512, 0, stream>>>(x,  csr, rowptr, invcnt, U1, V2a, cpa, hA);
    fused_layer<64><<<LAYER_BLOCKS, 512, 0, stream>>>(hA, csr, rowptr, invcnt, U2, V2b, cpb, hB);
    fused_layer<64><<<LAYER_BLOCKS, 512, 0, stream>>>(hB, csr, rowptr, invcnt, U3, V2c, cpc, hout);

    // heads
    heads_kernel<<<HEAD_BLOCKS, 256, 0, stream>>>(hout, Ws, bs, Wst, bst, Wo, bo, state, part);
    final_reduce<<<1, 1024, 0, stream>>>(part, scal);
}